// Round 8
// baseline (95.077 us; speedup 1.0000x reference)
//
#include <hip/hip_runtime.h>

// z: [32,64,32,32] fp32, codebook: [1024,64] fp32
#define C_DIM   64
#define K_CODES 1024
#define HW      1024
#define CHW     (C_DIM * HW)             // 65536
#define N_TOTAL 32768
#define CODES_ELEMS 2097152

#define THREADS 512                      // 8 waves: ktl = w&3 (k-split), nt = w>>2 (n-tile)
#define NBLK    64
#define NGROUPS 8

typedef _Float16 half8  __attribute__((ext_vector_type(8)));
typedef float    f32x16 __attribute__((ext_vector_type(16)));

#define WS_A_ELEMS 16384                 // half8 count: 256 KB A-frags

__device__ __forceinline__ bool better(float k1, int i1, float k2, int i2) {
    return (k1 > k2) || (k1 == k2 && i1 < i2);
}
__device__ __forceinline__ void merge2(float& bk, int& bi, float& sk, int& si,
                                       float obk, int obi, float osk, int osi) {
    if (better(obk, obi, bk, bi)) {
        float nsk; int nsi;
        if (better(bk, bi, osk, osi)) { nsk = bk; nsi = bi; } else { nsk = osk; nsi = osi; }
        bk = obk; bi = obi; sk = nsk; si = nsi;
    } else {
        if (better(obk, obi, sk, si)) { sk = obk; si = obi; }
    }
}

// One-shot prep: blocks 0..31 -> hi/lo fp16 A-fragment layout; block 32 -> cnorm.
__global__ void prep_kernel(const float* __restrict__ cb, half8* __restrict__ wsA,
                            float* __restrict__ wsCn) {
    if (blockIdx.x < 32) {
        const int tid = blockIdx.x * 256 + threadIdx.x;   // 0..8191
        const int kt = tid >> 8, q = (tid >> 6) & 3, l = tid & 63;
        const int k  = kt * 32 + (l & 31);
        const int c0 = q * 16 + (l >> 5) * 8;
        const float4* p = (const float4*)(cb + k * C_DIM + c0);
        float4 f0 = p[0], f1 = p[1];
        float v[8] = {f0.x,f0.y,f0.z,f0.w,f1.x,f1.y,f1.z,f1.w};
        half8 h8, l8;
#pragma unroll
        for (int j = 0; j < 8; ++j) {
            _Float16 hh = (_Float16)v[j];
            _Float16 ll = (_Float16)(v[j] - (float)hh);
            h8[j] = hh; l8[j] = ll;
        }
        wsA[((kt * 4 + q) * 2 + 0) * 64 + l] = h8;
        wsA[((kt * 4 + q) * 2 + 1) * 64 + l] = l8;
    } else {
#pragma unroll
        for (int rep = 0; rep < 4; ++rep) {
            const int k = threadIdx.x * 4 + rep;
            const float4* row = (const float4*)(cb + k * C_DIM);
            float r[8];
            {
                float4 f0 = row[0], f1 = row[1];
                float v[8] = {f0.x,f0.y,f0.z,f0.w,f1.x,f1.y,f1.z,f1.w};
#pragma unroll
                for (int j = 0; j < 8; ++j) r[j] = v[j]*v[j];
            }
#pragma unroll
            for (int i = 2; i < 16; i += 2) {
                float4 f0 = row[i], f1 = row[i+1];
                float v[8] = {f0.x,f0.y,f0.z,f0.w,f1.x,f1.y,f1.z,f1.w};
#pragma unroll
                for (int j = 0; j < 8; ++j) r[j] = fmaf(v[j], v[j], r[j]);
            }
            wsCn[k] = ((r[0]+r[1])+(r[2]+r[3])) + ((r[4]+r[5])+(r[6]+r[7]));
        }
    }
}

__attribute__((amdgpu_waves_per_eu(4, 4)))   // max=4 waves/EU: allocator free up to 128 VGPR
__launch_bounds__(THREADS)
__global__ void vq_kernel(const float* __restrict__ z, const float* __restrict__ cb,
                          const half8* __restrict__ wsA, const float* __restrict__ wsCn,
                          float* __restrict__ out) {
    __shared__ half8 sStage[1024];                 // 16 KB: B-frags
    __shared__ float sRed[2][4][32][4];
    __shared__ int   sCandA[NBLK];
    __shared__ int   sCandB[NBLK];
    __shared__ int   sIdxF[NBLK];

    const int t    = threadIdx.x;
    const int lane = t & 63;
    const int w    = t >> 6;
    const int ktl  = w & 3;
    const int nt   = w >> 2;
    const int base_n = blockIdx.x * NBLK;

    // ---- Stage B-fragments (x -> fp16 hi/lo) ----
    {
        const int nt_s = t >> 8, q = (t >> 6) & 3, l = t & 63;
        const int n_g = base_n + nt_s * 32 + (l & 31);
        const int bb = n_g >> 10, hwv = n_g & 1023;
        const int c0 = q * 16 + (l >> 5) * 8;
        half8 h8, l8;
#pragma unroll
        for (int j = 0; j < 8; ++j) {
            float v = z[bb * CHW + (c0 + j) * HW + hwv];
            _Float16 hh = (_Float16)v;
            _Float16 ll = (_Float16)(v - (float)hh);
            h8[j] = hh; l8[j] = ll;
        }
        sStage[((nt_s * 4 + q) * 2 + 0) * 64 + l] = h8;
        sStage[((nt_s * 4 + q) * 2 + 1) * 64 + l] = l8;
    }
    __syncthreads();

    half8 b_xh[4], b_xl[4];
#pragma unroll
    for (int q = 0; q < 4; ++q) {
        b_xh[q] = sStage[((nt * 4 + q) * 2 + 0) * 64 + lane];
        b_xl[q] = sStage[((nt * 4 + q) * 2 + 1) * 64 + lane];
    }

    // ---- k-group loop: acc initialized with exact fp32 -cn/2 (12 MFMAs/group).
    float bk0 = -3.4e38f, sk0 = -3.4e38f; int bi0 = 0, si0 = 0;
    float bk1 = -3.4e38f, sk1 = -3.4e38f; int bi1 = 0, si1 = 0;

#pragma unroll
    for (int g = 0; g < NGROUPS; ++g) {
        const int kt = g * 4 + ktl;
        half8 a_h[4], a_l[4];
#pragma unroll
        for (int q = 0; q < 4; ++q) {
            a_h[q] = wsA[((kt * 4 + q) * 2 + 0) * 64 + lane];
            a_l[q] = wsA[((kt * 4 + q) * 2 + 1) * 64 + lane];
        }
        // acc[r] = -0.5*cn[row(r)]; row(r) = (r&3) + 8*(r>>2) + 4*(lane>>5)
        f32x16 acc;
#pragma unroll
        for (int q = 0; q < 4; ++q) {
            float4 cq = *(const float4*)(wsCn + kt * 32 + 4 * (lane >> 5) + 8 * q);
            acc[4*q+0] = -0.5f * cq.x;
            acc[4*q+1] = -0.5f * cq.y;
            acc[4*q+2] = -0.5f * cq.z;
            acc[4*q+3] = -0.5f * cq.w;
        }

#pragma unroll
        for (int q = 0; q < 4; ++q) acc = __builtin_amdgcn_mfma_f32_32x32x16_f16(a_h[q], b_xh[q], acc, 0, 0, 0);
#pragma unroll
        for (int q = 0; q < 4; ++q) acc = __builtin_amdgcn_mfma_f32_32x32x16_f16(a_l[q], b_xh[q], acc, 0, 0, 0);
#pragma unroll
        for (int q = 0; q < 4; ++q) acc = __builtin_amdgcn_mfma_f32_32x32x16_f16(a_h[q], b_xl[q], acc, 0, 0, 0);

        const int kbase = kt * 32 + 4 * (lane >> 5);
#pragma unroll
        for (int r = 0; r < 8; ++r) {
            float v = acc[r];
            int ki = kbase + (r & 3) + 8 * (r >> 2);
            if (v > bk0)      { sk0 = bk0; si0 = bi0; bk0 = v; bi0 = ki; }
            else if (v > sk0) { sk0 = v; si0 = ki; }
        }
#pragma unroll
        for (int r = 8; r < 16; ++r) {
            float v = acc[r];
            int ki = kbase + (r & 3) + 8 * (r >> 2);
            if (v > bk1)      { sk1 = bk1; si1 = bi1; bk1 = v; bi1 = ki; }
            else if (v > sk1) { sk1 = v; si1 = ki; }
        }
    }

    // merge the two chains, then lane halves
    float bk = bk0, sk = sk0; int bi = bi0, si = si0;
    merge2(bk, bi, sk, si, bk1, bi1, sk1, si1);
    {
        float obk = __shfl_xor(bk, 32, 64); int obi = __shfl_xor(bi, 32, 64);
        float osk = __shfl_xor(sk, 32, 64); int osi = __shfl_xor(si, 32, 64);
        merge2(bk, bi, sk, si, obk, obi, osk, osi);
    }
    if (lane < 32) {
        sRed[nt][ktl][lane][0] = bk;
        sRed[nt][ktl][lane][1] = __int_as_float(bi);
        sRed[nt][ktl][lane][2] = sk;
        sRed[nt][ktl][lane][3] = __int_as_float(si);
    }
    __syncthreads();

    // ---- per-n partition merge -> top-2 candidates ----
    if (t < NBLK) {
        const int ntf = t >> 5, col = t & 31;
        float fbk = sRed[ntf][0][col][0]; int fbi = __float_as_int(sRed[ntf][0][col][1]);
        float fsk = sRed[ntf][0][col][2]; int fsi = __float_as_int(sRed[ntf][0][col][3]);
#pragma unroll
        for (int p = 1; p < 4; ++p)
            merge2(fbk, fbi, fsk, fsi,
                   sRed[ntf][p][col][0], __float_as_int(sRed[ntf][p][col][1]),
                   sRed[ntf][p][col][2], __float_as_int(sRed[ntf][p][col][3]));
        sCandA[t] = fbi;
        sCandB[t] = fsi;
    }
    __syncthreads();

    // ---- cooperative exact refinement: 8 lanes per n; xnorm cancels in d0-d1.
    {
        const int n_l = t >> 3, j = t & 7;
        const int c0i = sCandA[n_l], c1i = sCandB[n_l];
        const int n_g = base_n + n_l;
        const int bb = n_g >> 10, hwv = n_g & 1023;
        const float* zb = z + bb * CHW + hwv;
        float xv[8];
#pragma unroll
        for (int i = 0; i < 8; ++i) xv[i] = zb[(j * 8 + i) * HW];
        const float4* r0 = (const float4*)(cb + c0i * C_DIM + j * 8);
        const float4* r1 = (const float4*)(cb + c1i * C_DIM + j * 8);
        float4 a0 = r0[0], a1 = r0[1], b0 = r1[0], b1 = r1[1];
        float q0[8] = {a0.x,a0.y,a0.z,a0.w,a1.x,a1.y,a1.z,a1.w};
        float q1[8] = {b0.x,b0.y,b0.z,b0.w,b1.x,b1.y,b1.z,b1.w};
        float p0 = 0.f, p1 = 0.f;
#pragma unroll
        for (int i = 0; i < 8; ++i) {
            p0 = fmaf(xv[i], q0[i], p0);
            p1 = fmaf(xv[i], q1[i], p1);
        }
        p0 += __shfl_xor(p0, 1, 64); p0 += __shfl_xor(p0, 2, 64); p0 += __shfl_xor(p0, 4, 64);
        p1 += __shfl_xor(p1, 1, 64); p1 += __shfl_xor(p1, 2, 64); p1 += __shfl_xor(p1, 4, 64);
        if (j == 0) {
            float k0 = fmaf(-2.f, p0, wsCn[c0i]);   // d - xnorm (xnorm cancels)
            float k1 = fmaf(-2.f, p1, wsCn[c1i]);
            int win = (k1 < k0 || (k1 == k0 && c1i < c0i)) ? c1i : c0i;
            sIdxF[n_l] = win;
            out[CODES_ELEMS + n_g] = (float)win;
        }
    }
    __syncthreads();

    // ---- cooperative codes write: thread (n, chunk) reads 8 contiguous row
    // floats (8 rows x 128B per instr) and writes 8 x 32B segments.
    {
        const int n_l = t >> 3, j = t & 7;
        const int idx = sIdxF[n_l];
        const int n_g = base_n + n_l;
        const int bb = n_g >> 10, hwv = n_g & 1023;
        const float4* rp = (const float4*)(cb + idx * C_DIM + j * 8);
        float4 f0 = rp[0], f1 = rp[1];
        float vv[8] = {f0.x,f0.y,f0.z,f0.w,f1.x,f1.y,f1.z,f1.w};
        float* op = out + bb * CHW + hwv;
#pragma unroll
        for (int i = 0; i < 8; ++i) op[(j * 8 + i) * HW] = vv[i];
    }
}

extern "C" void kernel_launch(void* const* d_in, const int* in_sizes, int n_in,
                              void* d_out, int out_size, void* d_ws, size_t ws_size,
                              hipStream_t stream) {
    const float* z  = (const float*)d_in[0];
    const float* cb = (const float*)d_in[1];
    float* out = (float*)d_out;
    half8* wsA  = (half8*)d_ws;
    float* wsCn = (float*)((char*)d_ws + WS_A_ELEMS * sizeof(half8));

    prep_kernel<<<33, 256, 0, stream>>>(cb, wsA, wsCn);
    vq_kernel<<<N_TOTAL / NBLK, THREADS, 0, stream>>>(z, cb, wsA, wsCn, out);
}

// Round 9
// 93.994 us; speedup vs baseline: 1.0115x; 1.0115x over previous
//
#include <hip/hip_runtime.h>

// z: [32,64,32,32] fp32, codebook: [1024,64] fp32
#define C_DIM   64
#define K_CODES 1024
#define HW      1024
#define CHW     (C_DIM * HW)             // 65536
#define N_TOTAL 32768
#define CODES_ELEMS 2097152

#define THREADS 512                      // 8 waves: ktl = w&3 (k-split), nt = w>>2 (n-tile)
#define NBLK    64
#define NGROUPS 8

typedef _Float16 half8  __attribute__((ext_vector_type(8)));
typedef float    f32x16 __attribute__((ext_vector_type(16)));

#define WS_A_ELEMS 16384                 // half8 count: 256 KB A-frags

__device__ __forceinline__ bool better(float k1, int i1, float k2, int i2) {
    return (k1 > k2) || (k1 == k2 && i1 < i2);
}
__device__ __forceinline__ void merge2(float& bk, int& bi, float& sk, int& si,
                                       float obk, int obi, float osk, int osi) {
    if (better(obk, obi, bk, bi)) {
        float nsk; int nsi;
        if (better(bk, bi, osk, osi)) { nsk = bk; nsi = bi; } else { nsk = osk; nsi = osi; }
        bk = obk; bi = obi; sk = nsk; si = nsi;
    } else {
        if (better(obk, obi, sk, si)) { sk = obk; si = obi; }
    }
}

// One-shot prep: blocks 0..31 -> hi/lo fp16 A-fragment layout; block 32 -> cnorm.
__global__ void prep_kernel(const float* __restrict__ cb, half8* __restrict__ wsA,
                            float* __restrict__ wsCn) {
    if (blockIdx.x < 32) {
        const int tid = blockIdx.x * 256 + threadIdx.x;   // 0..8191
        const int kt = tid >> 8, q = (tid >> 6) & 3, l = tid & 63;
        const int k  = kt * 32 + (l & 31);
        const int c0 = q * 16 + (l >> 5) * 8;
        const float4* p = (const float4*)(cb + k * C_DIM + c0);
        float4 f0 = p[0], f1 = p[1];
        float v[8] = {f0.x,f0.y,f0.z,f0.w,f1.x,f1.y,f1.z,f1.w};
        half8 h8, l8;
#pragma unroll
        for (int j = 0; j < 8; ++j) {
            _Float16 hh = (_Float16)v[j];
            _Float16 ll = (_Float16)(v[j] - (float)hh);
            h8[j] = hh; l8[j] = ll;
        }
        wsA[((kt * 4 + q) * 2 + 0) * 64 + l] = h8;
        wsA[((kt * 4 + q) * 2 + 1) * 64 + l] = l8;
    } else {
#pragma unroll
        for (int rep = 0; rep < 4; ++rep) {
            const int k = threadIdx.x * 4 + rep;
            const float4* row = (const float4*)(cb + k * C_DIM);
            float r[8];
            {
                float4 f0 = row[0], f1 = row[1];
                float v[8] = {f0.x,f0.y,f0.z,f0.w,f1.x,f1.y,f1.z,f1.w};
#pragma unroll
                for (int j = 0; j < 8; ++j) r[j] = v[j]*v[j];
            }
#pragma unroll
            for (int i = 2; i < 16; i += 2) {
                float4 f0 = row[i], f1 = row[i+1];
                float v[8] = {f0.x,f0.y,f0.z,f0.w,f1.x,f1.y,f1.z,f1.w};
#pragma unroll
                for (int j = 0; j < 8; ++j) r[j] = fmaf(v[j], v[j], r[j]);
            }
            wsCn[k] = ((r[0]+r[1])+(r[2]+r[3])) + ((r[4]+r[5])+(r[6]+r[7]));
        }
    }
}

__launch_bounds__(THREADS)
__global__ void vq_kernel(const float* __restrict__ z, const float* __restrict__ cb,
                          const half8* __restrict__ wsA, const float* __restrict__ wsCn,
                          float* __restrict__ out) {
    __shared__ half8 sStage[1024];                 // 16 KB: B-frags (LDS-resident all loop)
    __shared__ float sCnorm[K_CODES];              // 4 KB
    __shared__ float sRed[2][4][32][4];
    __shared__ int   sCandA[NBLK];
    __shared__ int   sCandB[NBLK];
    __shared__ int   sIdxF[NBLK];

    const int t    = threadIdx.x;
    const int lane = t & 63;
    const int w    = t >> 6;
    const int ktl  = w & 3;
    const int nt   = w >> 2;
    const int base_n = blockIdx.x * NBLK;

    // ---- Stage B-fragments (x -> fp16 hi/lo) and cnorm into LDS ----
    {
        const int nt_s = t >> 8, q = (t >> 6) & 3, l = t & 63;
        const int n_g = base_n + nt_s * 32 + (l & 31);
        const int bb = n_g >> 10, hwv = n_g & 1023;
        const int c0 = q * 16 + (l >> 5) * 8;
        half8 h8, l8;
#pragma unroll
        for (int j = 0; j < 8; ++j) {
            float v = z[bb * CHW + (c0 + j) * HW + hwv];
            _Float16 hh = (_Float16)v;
            _Float16 ll = (_Float16)(v - (float)hh);
            h8[j] = hh; l8[j] = ll;
        }
        sStage[((nt_s * 4 + q) * 2 + 0) * 64 + l] = h8;
        sStage[((nt_s * 4 + q) * 2 + 1) * 64 + l] = l8;
    }
    if (t < 256) ((float4*)sCnorm)[t] = ((const float4*)wsCn)[t];
    __syncthreads();

    // ---- k-group loop. B-frags read from LDS per use (keeps live set < 64
    // VGPR: acc 16 + a 8 + b 8 transient + scan 12 -> no scratch spill,
    // which was the R6-R8 stall: 80-reg live set vs VGPR_Count=64).
    float bk0 = -3.4e38f, sk0 = -3.4e38f; int bi0 = 0, si0 = 0;
    float bk1 = -3.4e38f, sk1 = -3.4e38f; int bi1 = 0, si1 = 0;

#pragma unroll
    for (int g = 0; g < NGROUPS; ++g) {
        const int kt = g * 4 + ktl;
        // acc[4q+i] = -0.5*cn[kt*32 + 8q + 4*(lane>>5) + i]  (exact fp32 fold)
        f32x16 acc;
#pragma unroll
        for (int q = 0; q < 4; ++q) {
            float4 cq = *(const float4*)(sCnorm + kt * 32 + 8 * q + 4 * (lane >> 5));
            acc[4*q+0] = -0.5f * cq.x;
            acc[4*q+1] = -0.5f * cq.y;
            acc[4*q+2] = -0.5f * cq.z;
            acc[4*q+3] = -0.5f * cq.w;
        }
#pragma unroll
        for (int q = 0; q < 4; ++q) {
            half8 ah = wsA[((kt * 4 + q) * 2 + 0) * 64 + lane];
            half8 al = wsA[((kt * 4 + q) * 2 + 1) * 64 + lane];
            half8 bh = sStage[((nt * 4 + q) * 2 + 0) * 64 + lane];
            half8 bl = sStage[((nt * 4 + q) * 2 + 1) * 64 + lane];
            acc = __builtin_amdgcn_mfma_f32_32x32x16_f16(ah, bh, acc, 0, 0, 0);
            acc = __builtin_amdgcn_mfma_f32_32x32x16_f16(al, bh, acc, 0, 0, 0);
            acc = __builtin_amdgcn_mfma_f32_32x32x16_f16(ah, bl, acc, 0, 0, 0);
        }

        const int kbase = kt * 32 + 4 * (lane >> 5);
#pragma unroll
        for (int r = 0; r < 8; ++r) {
            float v = acc[r];
            int ki = kbase + (r & 3) + 8 * (r >> 2);
            if (v > bk0)      { sk0 = bk0; si0 = bi0; bk0 = v; bi0 = ki; }
            else if (v > sk0) { sk0 = v; si0 = ki; }
        }
#pragma unroll
        for (int r = 8; r < 16; ++r) {
            float v = acc[r];
            int ki = kbase + (r & 3) + 8 * (r >> 2);
            if (v > bk1)      { sk1 = bk1; si1 = bi1; bk1 = v; bi1 = ki; }
            else if (v > sk1) { sk1 = v; si1 = ki; }
        }
    }

    // merge the two chains, then lane halves
    float bk = bk0, sk = sk0; int bi = bi0, si = si0;
    merge2(bk, bi, sk, si, bk1, bi1, sk1, si1);
    {
        float obk = __shfl_xor(bk, 32, 64); int obi = __shfl_xor(bi, 32, 64);
        float osk = __shfl_xor(sk, 32, 64); int osi = __shfl_xor(si, 32, 64);
        merge2(bk, bi, sk, si, obk, obi, osk, osi);
    }
    if (lane < 32) {
        sRed[nt][ktl][lane][0] = bk;
        sRed[nt][ktl][lane][1] = __int_as_float(bi);
        sRed[nt][ktl][lane][2] = sk;
        sRed[nt][ktl][lane][3] = __int_as_float(si);
    }
    __syncthreads();

    // ---- per-n partition merge -> top-2 candidates ----
    if (t < NBLK) {
        const int ntf = t >> 5, col = t & 31;
        float fbk = sRed[ntf][0][col][0]; int fbi = __float_as_int(sRed[ntf][0][col][1]);
        float fsk = sRed[ntf][0][col][2]; int fsi = __float_as_int(sRed[ntf][0][col][3]);
#pragma unroll
        for (int p = 1; p < 4; ++p)
            merge2(fbk, fbi, fsk, fsi,
                   sRed[ntf][p][col][0], __float_as_int(sRed[ntf][p][col][1]),
                   sRed[ntf][p][col][2], __float_as_int(sRed[ntf][p][col][3]));
        sCandA[t] = fbi;
        sCandB[t] = fsi;
    }
    __syncthreads();

    // ---- cooperative exact refinement: 8 lanes per n; xnorm cancels in d0-d1.
    {
        const int n_l = t >> 3, j = t & 7;
        const int c0i = sCandA[n_l], c1i = sCandB[n_l];
        const int n_g = base_n + n_l;
        const int bb = n_g >> 10, hwv = n_g & 1023;
        const float* zb = z + bb * CHW + hwv;
        float xv[8];
#pragma unroll
        for (int i = 0; i < 8; ++i) xv[i] = zb[(j * 8 + i) * HW];
        const float4* r0 = (const float4*)(cb + c0i * C_DIM + j * 8);
        const float4* r1 = (const float4*)(cb + c1i * C_DIM + j * 8);
        float4 a0 = r0[0], a1 = r0[1], b0 = r1[0], b1 = r1[1];
        float q0[8] = {a0.x,a0.y,a0.z,a0.w,a1.x,a1.y,a1.z,a1.w};
        float q1[8] = {b0.x,b0.y,b0.z,b0.w,b1.x,b1.y,b1.z,b1.w};
        float p0 = 0.f, p1 = 0.f;
#pragma unroll
        for (int i = 0; i < 8; ++i) {
            p0 = fmaf(xv[i], q0[i], p0);
            p1 = fmaf(xv[i], q1[i], p1);
        }
        p0 += __shfl_xor(p0, 1, 64); p0 += __shfl_xor(p0, 2, 64); p0 += __shfl_xor(p0, 4, 64);
        p1 += __shfl_xor(p1, 1, 64); p1 += __shfl_xor(p1, 2, 64); p1 += __shfl_xor(p1, 4, 64);
        if (j == 0) {
            float k0 = fmaf(-2.f, p0, sCnorm[c0i]);   // d - xnorm (xnorm cancels)
            float k1 = fmaf(-2.f, p1, sCnorm[c1i]);
            int win = (k1 < k0 || (k1 == k0 && c1i < c0i)) ? c1i : c0i;
            sIdxF[n_l] = win;
            out[CODES_ELEMS + n_g] = (float)win;
        }
    }
    __syncthreads();

    // ---- cooperative codes write ----
    {
        const int n_l = t >> 3, j = t & 7;
        const int idx = sIdxF[n_l];
        const int n_g = base_n + n_l;
        const int bb = n_g >> 10, hwv = n_g & 1023;
        const float4* rp = (const float4*)(cb + idx * C_DIM + j * 8);
        float4 f0 = rp[0], f1 = rp[1];
        float vv[8] = {f0.x,f0.y,f0.z,f0.w,f1.x,f1.y,f1.z,f1.w};
        float* op = out + bb * CHW + hwv;
#pragma unroll
        for (int i = 0; i < 8; ++i) op[(j * 8 + i) * HW] = vv[i];
    }
}

extern "C" void kernel_launch(void* const* d_in, const int* in_sizes, int n_in,
                              void* d_out, int out_size, void* d_ws, size_t ws_size,
                              hipStream_t stream) {
    const float* z  = (const float*)d_in[0];
    const float* cb = (const float*)d_in[1];
    float* out = (float*)d_out;
    half8* wsA  = (half8*)d_ws;
    float* wsCn = (float*)((char*)d_ws + WS_A_ELEMS * sizeof(half8));

    prep_kernel<<<33, 256, 0, stream>>>(cb, wsA, wsCn);
    vq_kernel<<<N_TOTAL / NBLK, THREADS, 0, stream>>>(z, cb, wsA, wsCn, out);
}